// Round 10
// baseline (173.814 us; speedup 1.0000x reference)
//
#include <hip/hip_runtime.h>
#include <hip/hip_bf16.h>

#define NN 50000
#define FF 128
#define UU 128
#define NREL 8
#define NE 60000
#define NKEY (NREL * NN)        // 400000
#define NET (NREL * NE)         // 480000

typedef __attribute__((ext_vector_type(8))) short bf16x8;
typedef __attribute__((ext_vector_type(4))) float f32x4;

// ---------------- prep: X->bf16, W->fragment-layout bf16 ----------------
// Wf layout: for (m,c,s), a 1KB block at ((m*8+c)*4+s)*512 ushorts; lane
// (ag*16+al) holds 8 bf16 of W_m[k = s*32+ag*8+j][col = c*16+al], j=0..7.
// Every B-frag load in the GEMM phase is one coalesced 1KB dwordx4.

__global__ __launch_bounds__(256) void prep_kernel(
    const float* __restrict__ X, const float* __restrict__ Wself,
    const float* __restrict__ Wrel, ushort* __restrict__ Xb,
    ushort* __restrict__ Wf)
{
    int i = blockIdx.x * 256 + threadIdx.x;
    if (i < NN * FF / 4) {                      // X -> bf16
        float4 v = ((const float4*)X)[i];
        union { __hip_bfloat162 h[2]; uint2 u; } p;
        p.h[0] = __float22bfloat162_rn(make_float2(v.x, v.y));
        p.h[1] = __float22bfloat162_rn(make_float2(v.z, v.w));
        ((uint2*)Xb)[i] = p.u;
    }
    if (i < 9 * FF * UU) {                      // W -> fragment layout
        int m = i >> 14, k = (i >> 7) & 127, col = i & 127;
        int c = col >> 4, al = col & 15;
        int s = k >> 5, ag = (k >> 3) & 3, j = k & 7;
        float v = (m == 0) ? Wself[i] : Wrel[i - FF * UU];
        __hip_bfloat16 h = __float2bfloat16(v);
        Wf[((m * 8 + c) * 4 + s) * 512 + (ag * 16 + al) * 8 + j] = *(ushort*)&h;
    }
}

// ---------------- per-(rel,dst) linked list with packed records ----------------

__global__ __launch_bounds__(256) void build_kernel(
    const int* __restrict__ esrc, const int* __restrict__ edst,
    const float* __restrict__ ew, int* __restrict__ head, int4* __restrict__ rec)
{
    int i = blockIdx.x * 256 + threadIdx.x;
    if (i < NET) {
        int key = (i / NE) * NN + edst[i];      // const divisor -> magic mul
        int prev = atomicExch(&head[key], i);
        rec[i] = make_int4(esrc[i], __float_as_int(ew[i]), prev, 0);
    }
}

// ---------------- fused agg + GEMM ----------------
// Block = 4 waves = one 16-row output tile. Z[8 rels][16 rows][128] bf16 in
// LDS (32 KB), slot-swizzled t' = t ^ (row&15) (16B slots) so both agg writes
// and A-frag ds_read_b128 are <=2-way. Phase 1: wave w walks rels {2w,2w+1}
// (4-key interleaved list walks; consecutive keys -> int4 head load).
// Phase 2: m-split MFMA (wave w: m = w, w+4, w+8; m=0 A from Xb global),
// then LDS reduce (reusing Z space) + wave-0 bias/relu/store.
// D layout: col = c*16+al, row = R0 + ag*4 + q (verified rounds 5-9).

#define AGG_WALK(e, r, ax, ay)                                              \
    while (e >= 0) {                                                        \
        float w = __int_as_float(r.y);                                      \
        uint x = *(const uint*)(Xb + (size_t)r.x * FF + 2 * l);             \
        e = r.z;                                                            \
        if (e >= 0) r = rec[e];                                             \
        ax = fmaf(__uint_as_float(x << 16), w, ax);                         \
        ay = fmaf(__uint_as_float(x & 0xffff0000u), w, ay);                 \
    }

__global__ __launch_bounds__(256, 4) void rgcn_kernel(
    const ushort* __restrict__ Xb, const ushort* __restrict__ Wf,
    const int* __restrict__ head, const int4* __restrict__ rec,
    const float* __restrict__ bias, float* __restrict__ out)
{
    __shared__ ushort zs[NREL * 16 * FF];       // 32 KB; reused as reduce buf
    const int R0 = blockIdx.x * 16;             // NN % 16 == 0
    const int wid = threadIdx.x >> 6;
    const int l = threadIdx.x & 63;

    // ---- phase 1: aggregation into LDS Z ----
    {
        const int t = l >> 2;                   // 16B slot within row
        const int o = (l & 3) * 2;              // ushort offset within slot
        #pragma unroll
        for (int rr = 0; rr < 2; ++rr) {
            const int rel = 2 * wid + rr;
            #pragma unroll
            for (int rb = 0; rb < 4; ++rb) {
                const int row0 = rb * 4;
                const int k0 = rel * NN + R0 + row0;    // k0 % 4 == 0
                int4 hv = *(const int4*)&head[k0];      // 4 consecutive heads
                int e0 = hv.x, e1 = hv.y, e2 = hv.z, e3 = hv.w;
                int4 r0, r1, r2, r3;
                if (e0 >= 0) r0 = rec[e0];
                if (e1 >= 0) r1 = rec[e1];
                if (e2 >= 0) r2 = rec[e2];
                if (e3 >= 0) r3 = rec[e3];
                float a0x = 0.f, a0y = 0.f, a1x = 0.f, a1y = 0.f;
                float a2x = 0.f, a2y = 0.f, a3x = 0.f, a3y = 0.f;
                AGG_WALK(e0, r0, a0x, a0y)
                AGG_WALK(e1, r1, a1x, a1y)
                AGG_WALK(e2, r2, a2x, a2y)
                AGG_WALK(e3, r3, a3x, a3y)
                __hip_bfloat162 h;
                int row, base;
                row = row0 + 0; base = (rel * 16 + row) * 128;
                h = __float22bfloat162_rn(make_float2(a0x, a0y));
                *(uint*)&zs[base + ((t ^ (row & 15)) * 8) + o] = *(uint*)&h;
                row = row0 + 1; base = (rel * 16 + row) * 128;
                h = __float22bfloat162_rn(make_float2(a1x, a1y));
                *(uint*)&zs[base + ((t ^ (row & 15)) * 8) + o] = *(uint*)&h;
                row = row0 + 2; base = (rel * 16 + row) * 128;
                h = __float22bfloat162_rn(make_float2(a2x, a2y));
                *(uint*)&zs[base + ((t ^ (row & 15)) * 8) + o] = *(uint*)&h;
                row = row0 + 3; base = (rel * 16 + row) * 128;
                h = __float22bfloat162_rn(make_float2(a3x, a3y));
                *(uint*)&zs[base + ((t ^ (row & 15)) * 8) + o] = *(uint*)&h;
            }
        }
    }
    __syncthreads();

    // ---- phase 2: m-split GEMM ----
    const int al = l & 15;
    const int ag = l >> 4;
    f32x4 acc[8];
    #pragma unroll
    for (int c = 0; c < 8; ++c) acc[c] = (f32x4){0.f, 0.f, 0.f, 0.f};

    const bf16x8* Wf8 = (const bf16x8*)Wf;
    #pragma unroll
    for (int mm = 0; mm < 3; ++mm) {
        const int m = wid + mm * 4;             // wave-uniform
        if (m < 9) {
            bf16x8 afr[4];
            if (m == 0) {
                const ushort* Arow = Xb + (size_t)(R0 + al) * FF;
                #pragma unroll
                for (int s = 0; s < 4; ++s)
                    afr[s] = *(const bf16x8*)(Arow + s * 32 + ag * 8);
            } else {
                const int base = ((m - 1) * 16 + al) * 128;
                #pragma unroll
                for (int s = 0; s < 4; ++s) {
                    int t2 = (s * 4 + ag) ^ (al & 15);
                    afr[s] = *(const bf16x8*)&zs[base + t2 * 8];
                }
            }
            #pragma unroll
            for (int c = 0; c < 8; ++c) {
                #pragma unroll
                for (int s = 0; s < 4; ++s) {
                    bf16x8 bfr = Wf8[((m * 8 + c) * 4 + s) * 64 + l];
                    acc[c] = __builtin_amdgcn_mfma_f32_16x16x32_bf16(
                        afr[s], bfr, acc[c], 0, 0, 0);
                }
            }
        }
    }

    __syncthreads();                            // all Z reads done; reuse zs
    f32x4* red = (f32x4*)zs;                    // 3 waves x 512 f32x4 = 24 KB
    if (wid > 0) {
        f32x4* slot = red + (wid - 1) * 512 + l * 8;
        #pragma unroll
        for (int c = 0; c < 8; ++c) slot[c ^ (l & 7)] = acc[c];
    }
    __syncthreads();
    if (wid == 0) {
        #pragma unroll
        for (int w = 0; w < 3; ++w) {
            const f32x4* slot = red + w * 512 + l * 8;
            #pragma unroll
            for (int c = 0; c < 8; ++c) acc[c] += slot[c ^ (l & 7)];
        }
        #pragma unroll
        for (int c = 0; c < 8; ++c) {
            int col = c * 16 + al;
            float b = bias[col];
            #pragma unroll
            for (int q = 0; q < 4; ++q) {
                int row = R0 + ag * 4 + q;
                out[(size_t)row * UU + col] = fmaxf(acc[c][q] + b, 0.f);
            }
        }
    }
}

// ---------------- launch ----------------

extern "C" void kernel_launch(void* const* d_in, const int* in_sizes, int n_in,
                              void* d_out, int out_size, void* d_ws, size_t ws_size,
                              hipStream_t stream) {
    const float* X     = (const float*)d_in[0];
    const int*   esrc  = (const int*)d_in[1];
    const int*   edst  = (const int*)d_in[2];
    const float* ew    = (const float*)d_in[3];
    const float* Wself = (const float*)d_in[4];
    const float* Wrel  = (const float*)d_in[5];
    const float* bias  = (const float*)d_in[6];
    float* out = (float*)d_out;

    // ws layout (16B-aligned segments), ~22.4 MB total
    ushort* Xb   = (ushort*)d_ws;               // NN*FF bf16   = 12.8 MB
    ushort* Wf   = Xb + (size_t)NN * FF;        // 9*FF*UU bf16 = 0.29 MB
    int*    head = (int*)(Wf + 9 * FF * UU);    // NKEY         = 1.6 MB
    int4*   rec  = (int4*)(head + NKEY);        // NET int4     = 7.7 MB

    hipMemsetAsync(head, 0xFF, NKEY * sizeof(int), stream);   // head = -1
    hipLaunchKernelGGL(prep_kernel,  dim3(NN * FF / 4 / 256), dim3(256), 0, stream,
                       X, Wself, Wrel, Xb, Wf);
    hipLaunchKernelGGL(build_kernel, dim3((NET + 255) / 256), dim3(256), 0, stream,
                       esrc, edst, ew, head, rec);
    hipLaunchKernelGGL(rgcn_kernel,  dim3(NN / 16), dim3(256), 0, stream,
                       Xb, Wf, head, rec, bias, out);
}

// Round 11
// 163.152 us; speedup vs baseline: 1.0654x; 1.0654x over previous
//
#include <hip/hip_runtime.h>
#include <hip/hip_bf16.h>

#define NN 50000
#define FF 128
#define UU 128
#define NREL 8
#define NE 60000
#define NKEY (NREL * NN)        // 400000
#define NET (NREL * NE)         // 480000

typedef __attribute__((ext_vector_type(8))) short bf16x8;
typedef __attribute__((ext_vector_type(4))) float f32x4;

// ---------------- prep: X->bf16, W->fragment layout, zero cnt/gcur ----------------
// Wf layout: for (m,c,s), a 1KB block at ((m*8+c)*4+s)*512 ushorts; lane
// (ag*16+al) holds 8 bf16 of W_m[k = s*32+ag*8+j][col = c*16+al], j=0..7.

__global__ __launch_bounds__(256) void prep_kernel(
    const float* __restrict__ X, const float* __restrict__ Wself,
    const float* __restrict__ Wrel, ushort* __restrict__ Xb,
    ushort* __restrict__ Wf, int* __restrict__ cnt, int* __restrict__ gcur)
{
    int i = blockIdx.x * 256 + threadIdx.x;
    if (i < NN * FF / 4) {                      // X -> bf16
        float4 v = ((const float4*)X)[i];
        union { __hip_bfloat162 h[2]; uint2 u; } p;
        p.h[0] = __float22bfloat162_rn(make_float2(v.x, v.y));
        p.h[1] = __float22bfloat162_rn(make_float2(v.z, v.w));
        ((uint2*)Xb)[i] = p.u;
    }
    if (i < NKEY) cnt[i] = 0;
    if (i == 0) *gcur = 0;
    if (i < 9 * FF * UU) {                      // W -> fragment layout
        int m = i >> 14, k = (i >> 7) & 127, col = i & 127;
        int c = col >> 4, al = col & 15;
        int s = k >> 5, ag = (k >> 3) & 3, j = k & 7;
        float v = (m == 0) ? Wself[i] : Wrel[i - FF * UU];
        __hip_bfloat16 h = __float2bfloat16(v);
        Wf[((m * 8 + c) * 4 + s) * 512 + (ag * 16 + al) * 8 + j] = *(ushort*)&h;
    }
}

// ---------------- CSR build: count -> fused scan(+atomic base) -> fill -----------

__global__ __launch_bounds__(256) void count_kernel(
    const int* __restrict__ edst, int* __restrict__ cnt)
{
    int i = blockIdx.x * 256 + threadIdx.x;
    if (i < NET) {
        int rel = i / NE;                       // const divisor -> magic mul
        atomicAdd(&cnt[rel * NN + edst[i]], 1);
    }
}

// per-256-block exclusive scan; block base from a global atomic counter.
// Key-major contiguity holds WITHIN each 256-key block, which is all agg needs
// (4-key batches never straddle a block).
__global__ __launch_bounds__(256) void scan_kernel(
    const int* __restrict__ cnt, int* __restrict__ off, int* __restrict__ cur,
    int* __restrict__ gcur)
{
    __shared__ int s0[256], s1[256];
    __shared__ int sbase;
    const int t = threadIdx.x;
    const int gi = blockIdx.x * 256 + t;
    s0[t] = (gi < NKEY) ? cnt[gi] : 0;
    __syncthreads();
    int* src = s0; int* dst = s1;
    #pragma unroll
    for (int d = 1; d < 256; d <<= 1) {
        dst[t] = src[t] + (t >= d ? src[t - d] : 0);
        __syncthreads();
        int* tmp = src; src = dst; dst = tmp;
    }
    if (t == 255) sbase = atomicAdd(gcur, src[255]);
    __syncthreads();
    int v = (t ? src[t - 1] : 0) + sbase;
    if (gi < NKEY) { off[gi] = v; cur[gi] = v; }
}

__global__ __launch_bounds__(256) void fill_kernel(
    const int* __restrict__ esrc, const int* __restrict__ edst,
    const float* __restrict__ ew, int* __restrict__ cur, int2* __restrict__ rec)
{
    int i = blockIdx.x * 256 + threadIdx.x;
    if (i < NET) {
        int rel = i / NE;
        int pos = atomicAdd(&cur[rel * NN + edst[i]], 1);
        rec[pos] = make_int2(esrc[i], __float_as_int(ew[i]));
    }
}

// ---------------- pass 1: aggregation, one wave per 4 consecutive keys ----------
// CSR gives parallel (chain-free) rec loads: up to 8 recs + 8 X-rows in flight.
// Lane l owns ushorts 2l,2l+1 of the 128-wide row.

#define LOADR(i) int2 r##i = make_int2(0, 0); if (i < n) r##i = R[i];
#define LOADX(i) uint x##i = 0; if (i < n) \
    x##i = *(const uint*)(Xb + (size_t)r##i.x * FF + 2 * l);
#define ACCE(i)                                                              \
    if (i < n) {                                                             \
        float w = __int_as_float(r##i.y);                                    \
        float vx = __uint_as_float(x##i << 16);                              \
        float vy = __uint_as_float(x##i & 0xffff0000u);                      \
        if (i < b0)      { a0x = fmaf(vx,w,a0x); a0y = fmaf(vy,w,a0y); }     \
        else if (i < b1) { a1x = fmaf(vx,w,a1x); a1y = fmaf(vy,w,a1y); }     \
        else if (i < b2) { a2x = fmaf(vx,w,a2x); a2y = fmaf(vy,w,a2y); }     \
        else             { a3x = fmaf(vx,w,a3x); a3y = fmaf(vy,w,a3y); }     \
    }

__global__ __launch_bounds__(256) void agg_kernel(
    const ushort* __restrict__ Xb, const int* __restrict__ off,
    const int* __restrict__ cnt, const int2* __restrict__ rec,
    ushort* __restrict__ Zb)
{
    const int gwid = (blockIdx.x * 256 + threadIdx.x) >> 6;
    const int l = threadIdx.x & 63;
    const int k0 = gwid * 4;

    const int4 c4 = *(const int4*)&cnt[k0];
    const int4 o4 = *(const int4*)&off[k0];
    const int b0 = c4.x, b1 = b0 + c4.y, b2 = b1 + c4.z;
    const int n = b2 + c4.w;
    const int2* R = rec + o4.x;

    float a0x = 0.f, a0y = 0.f, a1x = 0.f, a1y = 0.f;
    float a2x = 0.f, a2y = 0.f, a3x = 0.f, a3y = 0.f;

    // parallel batch of up to 8 edges (covers ~95% of batches fully)
    LOADR(0) LOADR(1) LOADR(2) LOADR(3) LOADR(4) LOADR(5) LOADR(6) LOADR(7)
    LOADX(0) LOADX(1) LOADX(2) LOADX(3) LOADX(4) LOADX(5) LOADX(6) LOADX(7)
    ACCE(0) ACCE(1) ACCE(2) ACCE(3) ACCE(4) ACCE(5) ACCE(6) ACCE(7)

    for (int j = 8; j < n; ++j) {               // rare spill (P ~ 5%)
        int2 rr = R[j];
        uint xx = *(const uint*)(Xb + (size_t)rr.x * FF + 2 * l);
        float w = __int_as_float(rr.y);
        float vx = __uint_as_float(xx << 16);
        float vy = __uint_as_float(xx & 0xffff0000u);
        if (j < b0)      { a0x = fmaf(vx,w,a0x); a0y = fmaf(vy,w,a0y); }
        else if (j < b1) { a1x = fmaf(vx,w,a1x); a1y = fmaf(vy,w,a1y); }
        else if (j < b2) { a2x = fmaf(vx,w,a2x); a2y = fmaf(vy,w,a2y); }
        else             { a3x = fmaf(vx,w,a3x); a3y = fmaf(vy,w,a3y); }
    }

    __hip_bfloat162 h;
    h = __float22bfloat162_rn(make_float2(a0x, a0y));
    *(uint*)(Zb + (size_t)(k0 + 0) * FF + 2 * l) = *(uint*)&h;
    h = __float22bfloat162_rn(make_float2(a1x, a1y));
    *(uint*)(Zb + (size_t)(k0 + 1) * FF + 2 * l) = *(uint*)&h;
    h = __float22bfloat162_rn(make_float2(a2x, a2y));
    *(uint*)(Zb + (size_t)(k0 + 2) * FF + 2 * l) = *(uint*)&h;
    h = __float22bfloat162_rn(make_float2(a3x, a3y));
    *(uint*)(Zb + (size_t)(k0 + 3) * FF + 2 * l) = *(uint*)&h;
}

// ---------------- pass 2: GEMM with LDS-staged W ----------------
// Block = 4 waves, wave = one 16-row tile. Per m: reg-staged 32KB Wf plane
// into LDS (next-m global loads issued before compute -> latency hidden),
// B-frags via conflict-free ds_read_b128 (lane l reads bytes l*16 of its 1KB
// frag block). A-frags from Xb/Zb global (L3-resident). D layout verified
// rounds 5-9: col = c*16+al, row = R0 + ag*4 + q.

__global__ __launch_bounds__(256, 3) void gemm_kernel(
    const ushort* __restrict__ Xb, const ushort* __restrict__ Zb,
    const ushort* __restrict__ Wf, const float* __restrict__ bias,
    float* __restrict__ out)
{
    __shared__ uint4 bsh[2048];                 // 32 KB: one 32KB Wf plane
    const int t = threadIdx.x;
    const int wid = t >> 6;
    const int l = t & 63;
    const int gw0 = blockIdx.x * 4 + wid;
    const int gwid = (gw0 < NN / 16) ? gw0 : NN / 16 - 1;  // dup tail, benign
    const int R0 = gwid * 16;
    const int al = l & 15;
    const int ag = l >> 4;

    const uint4* Wf4 = (const uint4*)Wf;

    f32x4 acc[8];
    #pragma unroll
    for (int c = 0; c < 8; ++c) acc[c] = (f32x4){0.f, 0.f, 0.f, 0.f};

    uint4 stg0 = Wf4[t +    0], stg1 = Wf4[t +  256];
    uint4 stg2 = Wf4[t +  512], stg3 = Wf4[t +  768];
    uint4 stg4 = Wf4[t + 1024], stg5 = Wf4[t + 1280];
    uint4 stg6 = Wf4[t + 1536], stg7 = Wf4[t + 1792];

    for (int m = 0; m < 9; ++m) {
        __syncthreads();                        // previous m's reads done
        bsh[t +    0] = stg0; bsh[t +  256] = stg1;
        bsh[t +  512] = stg2; bsh[t +  768] = stg3;
        bsh[t + 1024] = stg4; bsh[t + 1280] = stg5;
        bsh[t + 1536] = stg6; bsh[t + 1792] = stg7;
        if (m < 8) {
            const uint4* Wn = Wf4 + (m + 1) * 2048;
            stg0 = Wn[t +    0]; stg1 = Wn[t +  256];
            stg2 = Wn[t +  512]; stg3 = Wn[t +  768];
            stg4 = Wn[t + 1024]; stg5 = Wn[t + 1280];
            stg6 = Wn[t + 1536]; stg7 = Wn[t + 1792];
        }
        bf16x8 afr[4];
        const ushort* Arow = (m == 0)
            ? Xb + (size_t)(R0 + al) * FF
            : Zb + ((size_t)(m - 1) * NN + R0 + al) * FF;
        #pragma unroll
        for (int s = 0; s < 4; ++s)
            afr[s] = *(const bf16x8*)(Arow + s * 32 + ag * 8);
        __syncthreads();                        // ds_writes visible
        #pragma unroll
        for (int c = 0; c < 8; ++c) {
            #pragma unroll
            for (int s = 0; s < 4; ++s) {
                bf16x8 bfr = *(const bf16x8*)&bsh[(c * 4 + s) * 64 + l];
                acc[c] = __builtin_amdgcn_mfma_f32_16x16x32_bf16(
                    afr[s], bfr, acc[c], 0, 0, 0);
            }
        }
    }

    #pragma unroll
    for (int c = 0; c < 8; ++c) {
        int col = c * 16 + al;
        float b = bias[col];
        #pragma unroll
        for (int q = 0; q < 4; ++q) {
            int row = R0 + ag * 4 + q;
            out[(size_t)row * UU + col] = fmaxf(acc[c][q] + b, 0.f);
        }
    }
}

// ---------------- launch ----------------

extern "C" void kernel_launch(void* const* d_in, const int* in_sizes, int n_in,
                              void* d_out, int out_size, void* d_ws, size_t ws_size,
                              hipStream_t stream) {
    const float* X     = (const float*)d_in[0];
    const int*   esrc  = (const int*)d_in[1];
    const int*   edst  = (const int*)d_in[2];
    const float* ew    = (const float*)d_in[3];
    const float* Wself = (const float*)d_in[4];
    const float* Wrel  = (const float*)d_in[5];
    const float* bias  = (const float*)d_in[6];
    float* out = (float*)d_out;

    // ws layout (16B-aligned segments), ~125 MB total
    ushort* Zb   = (ushort*)d_ws;               // NKEY*FF bf16 = 102.4 MB
    ushort* Xb   = Zb + (size_t)NKEY * FF;      // NN*FF bf16   = 12.8 MB
    ushort* Wf   = Xb + (size_t)NN * FF;        // 9*FF*UU bf16 = 0.29 MB
    int*    cnt  = (int*)(Wf + 9 * FF * UU);    // NKEY
    int*    off  = cnt + NKEY;                  // NKEY
    int*    cur  = off + NKEY;                  // NKEY
    int2*   rec  = (int2*)(cur + NKEY);         // NET int2 = 3.84 MB
    int*    gcur = (int*)(rec + NET);           // 1

    const int gKey  = (NKEY + 255) / 256;       // 1563
    const int gEdge = (NET + 255) / 256;        // 1875

    hipLaunchKernelGGL(prep_kernel,  dim3(NN * FF / 4 / 256), dim3(256), 0, stream,
                       X, Wself, Wrel, Xb, Wf, cnt, gcur);
    hipLaunchKernelGGL(count_kernel, dim3(gEdge), dim3(256), 0, stream, edst, cnt);
    hipLaunchKernelGGL(scan_kernel,  dim3(gKey),  dim3(256), 0, stream,
                       cnt, off, cur, gcur);
    hipLaunchKernelGGL(fill_kernel,  dim3(gEdge), dim3(256), 0, stream,
                       esrc, edst, ew, cur, rec);
    hipLaunchKernelGGL(agg_kernel,   dim3(NKEY / 16), dim3(256), 0, stream,
                       Xb, off, cnt, rec, Zb);
    hipLaunchKernelGGL(gemm_kernel,  dim3((NN / 16 + 3) / 4), dim3(256), 0, stream,
                       Xb, Zb, Wf, bias, out);
}

// Round 12
// 127.110 us; speedup vs baseline: 1.3674x; 1.2835x over previous
//
#include <hip/hip_runtime.h>
#include <hip/hip_bf16.h>

#define NN 50000
#define FF 128
#define UU 128
#define NREL 8
#define NE 60000
#define NKEY (NREL * NN)        // 400000
#define NET (NREL * NE)         // 480000

typedef __attribute__((ext_vector_type(8))) short bf16x8;
typedef __attribute__((ext_vector_type(4))) float f32x4;

// ---------------- prep: X->bf16, W->fragment layout, head = -1 ----------------
// Wf layout: for (m,c,s), a 1KB block at ((m*8+c)*4+s)*512 ushorts; lane
// (ag*16+al) holds 8 bf16 of W_m[k = s*32+ag*8+j][col = c*16+al], j=0..7.

__global__ __launch_bounds__(256) void prep_kernel(
    const float* __restrict__ X, const float* __restrict__ Wself,
    const float* __restrict__ Wrel, ushort* __restrict__ Xb,
    ushort* __restrict__ Wf, int* __restrict__ head)
{
    int i = blockIdx.x * 256 + threadIdx.x;
    if (i < NN * FF / 4) {                      // X -> bf16
        float4 v = ((const float4*)X)[i];
        union { __hip_bfloat162 h[2]; uint2 u; } p;
        p.h[0] = __float22bfloat162_rn(make_float2(v.x, v.y));
        p.h[1] = __float22bfloat162_rn(make_float2(v.z, v.w));
        ((uint2*)Xb)[i] = p.u;
    }
    if (i < NKEY) head[i] = -1;
    if (i < 9 * FF * UU) {                      // W -> fragment layout
        int m = i >> 14, k = (i >> 7) & 127, col = i & 127;
        int c = col >> 4, al = col & 15;
        int s = k >> 5, ag = (k >> 3) & 3, j = k & 7;
        float v = (m == 0) ? Wself[i] : Wrel[i - FF * UU];
        __hip_bfloat16 h = __float2bfloat16(v);
        Wf[((m * 8 + c) * 4 + s) * 512 + (ag * 16 + al) * 8 + j] = *(ushort*)&h;
    }
}

// ---------------- per-(rel,dst) linked list with packed records ----------------

__global__ __launch_bounds__(256) void build_kernel(
    const int* __restrict__ esrc, const int* __restrict__ edst,
    const float* __restrict__ ew, int* __restrict__ head, int4* __restrict__ rec)
{
    int i = blockIdx.x * 256 + threadIdx.x;
    if (i < NET) {
        int key = (i / NE) * NN + edst[i];      // const divisor -> magic mul
        int prev = atomicExch(&head[key], i);
        rec[i] = make_int4(esrc[i], __float_as_int(ew[i]), prev, 0);
    }
}

// ---------------- pass 1: aggregation, one wave per 4 consecutive keys ----------
// Zb[key][0:128) = bf16( sum w * X[src] ); zeros if list empty. Lane l owns
// ushorts 2l, 2l+1. Heads (one int4) + root recs prefetched for all 4 keys,
// then each walk issues next-rec before its FMAs (X-load || rec-load).

#define AGG_WALK(e, r, ax, ay)                                              \
    while (e >= 0) {                                                        \
        float w = __int_as_float(r.y);                                      \
        uint x = *(const uint*)(Xb + (size_t)r.x * FF + 2 * l);             \
        e = r.z;                                                            \
        if (e >= 0) r = rec[e];                                             \
        ax = fmaf(__uint_as_float(x << 16), w, ax);                         \
        ay = fmaf(__uint_as_float(x & 0xffff0000u), w, ay);                 \
    }

__global__ __launch_bounds__(256) void agg_kernel(
    const ushort* __restrict__ Xb, const int* __restrict__ head,
    const int4* __restrict__ rec, ushort* __restrict__ Zb)
{
    const int k0 = ((blockIdx.x * 256 + threadIdx.x) >> 6) * 4;
    const int l = threadIdx.x & 63;

    float a0x = 0.f, a0y = 0.f, a1x = 0.f, a1y = 0.f;
    float a2x = 0.f, a2y = 0.f, a3x = 0.f, a3y = 0.f;

    const int4 hv = *(const int4*)&head[k0];
    int e0 = hv.x, e1 = hv.y, e2 = hv.z, e3 = hv.w;
    int4 r0, r1, r2, r3;
    if (e0 >= 0) r0 = rec[e0];
    if (e1 >= 0) r1 = rec[e1];
    if (e2 >= 0) r2 = rec[e2];
    if (e3 >= 0) r3 = rec[e3];

    AGG_WALK(e0, r0, a0x, a0y)
    AGG_WALK(e1, r1, a1x, a1y)
    AGG_WALK(e2, r2, a2x, a2y)
    AGG_WALK(e3, r3, a3x, a3y)

    __hip_bfloat162 h;
    h = __float22bfloat162_rn(make_float2(a0x, a0y));
    *(uint*)(Zb + (size_t)(k0 + 0) * FF + 2 * l) = *(uint*)&h;
    h = __float22bfloat162_rn(make_float2(a1x, a1y));
    *(uint*)(Zb + (size_t)(k0 + 1) * FF + 2 * l) = *(uint*)&h;
    h = __float22bfloat162_rn(make_float2(a2x, a2y));
    *(uint*)(Zb + (size_t)(k0 + 2) * FF + 2 * l) = *(uint*)&h;
    h = __float22bfloat162_rn(make_float2(a3x, a3y));
    *(uint*)(Zb + (size_t)(k0 + 3) * FF + 2 * l) = *(uint*)&h;
}

// ---------------- pass 2: GEMM with LDS-staged W + A double-buffer ----------------
// Block = 4 waves, wave = one 16-row tile. Per m: W plane staged via regs into
// one 32KB LDS buffer (next plane prefetched into regs), A-frags for m+1
// loaded into the off-parity register set BEFORE m's MFMA burst -> HBM latency
// hides under MFMA + ds_read + barrier. Fully unrolled m-loop keeps aA/aB
// indices static (registers, no scratch). D: col=c*16+al, row=R0+ag*4+q.

#define LOAD_A(AF, P)                                                        \
    _Pragma("unroll")                                                        \
    for (int s = 0; s < 4; ++s)                                              \
        AF[s] = *(const bf16x8*)((P) + s * 32 + ag * 8);

#define MFMA_BURST(AF)                                                       \
    _Pragma("unroll")                                                        \
    for (int c = 0; c < 8; ++c) {                                            \
        _Pragma("unroll")                                                    \
        for (int s = 0; s < 4; ++s) {                                        \
            bf16x8 bfr = *(const bf16x8*)&bsh[(c * 4 + s) * 64 + l];         \
            acc[c] = __builtin_amdgcn_mfma_f32_16x16x32_bf16(                \
                AF[s], bfr, acc[c], 0, 0, 0);                                \
        }                                                                    \
    }

__global__ __launch_bounds__(256, 3) void gemm_kernel(
    const ushort* __restrict__ Xb, const ushort* __restrict__ Zb,
    const ushort* __restrict__ Wf, const float* __restrict__ bias,
    float* __restrict__ out)
{
    __shared__ uint4 bsh[2048];                 // 32 KB: one Wf plane
    const int t = threadIdx.x;
    const int wid = t >> 6;
    const int l = t & 63;
    const int gw0 = blockIdx.x * 4 + wid;
    const int gwid = (gw0 < NN / 16) ? gw0 : NN / 16 - 1;  // dup tail, benign
    const int R0 = gwid * 16;
    const int al = l & 15;
    const int ag = l >> 4;

    const uint4* Wf4 = (const uint4*)Wf;

    f32x4 acc[8];
    #pragma unroll
    for (int c = 0; c < 8; ++c) acc[c] = (f32x4){0.f, 0.f, 0.f, 0.f};

    // prologue: W[0] into stg regs, A[0] (Xb) into aA
    uint4 stg0 = Wf4[t +    0], stg1 = Wf4[t +  256];
    uint4 stg2 = Wf4[t +  512], stg3 = Wf4[t +  768];
    uint4 stg4 = Wf4[t + 1024], stg5 = Wf4[t + 1280];
    uint4 stg6 = Wf4[t + 1536], stg7 = Wf4[t + 1792];

    bf16x8 aA[4], aB[4];
    {
        const ushort* A0 = Xb + (size_t)(R0 + al) * FF;
        LOAD_A(aA, A0)
    }

    #pragma unroll
    for (int m = 0; m < 9; ++m) {
        __syncthreads();                        // prev MFMA done reading bsh
        bsh[t +    0] = stg0; bsh[t +  256] = stg1;
        bsh[t +  512] = stg2; bsh[t +  768] = stg3;
        bsh[t + 1024] = stg4; bsh[t + 1280] = stg5;
        bsh[t + 1536] = stg6; bsh[t + 1792] = stg7;
        if (m < 8) {                            // prefetch W[m+1]
            const uint4* Wn = Wf4 + (m + 1) * 2048;
            stg0 = Wn[t +    0]; stg1 = Wn[t +  256];
            stg2 = Wn[t +  512]; stg3 = Wn[t +  768];
            stg4 = Wn[t + 1024]; stg5 = Wn[t + 1280];
            stg6 = Wn[t + 1536]; stg7 = Wn[t + 1792];
        }
        if (m < 8) {                            // prefetch A[m+1] (Zb plane m)
            const ushort* An = Zb + ((size_t)m * NN + R0 + al) * FF;
            if ((m & 1) == 0) { LOAD_A(aB, An) } else { LOAD_A(aA, An) }
        }
        __syncthreads();                        // bsh writes visible
        if ((m & 1) == 0) { MFMA_BURST(aA) } else { MFMA_BURST(aB) }
    }

    #pragma unroll
    for (int c = 0; c < 8; ++c) {
        int col = c * 16 + al;
        float b = bias[col];
        #pragma unroll
        for (int q = 0; q < 4; ++q) {
            int row = R0 + ag * 4 + q;
            out[(size_t)row * UU + col] = fmaxf(acc[c][q] + b, 0.f);
        }
    }
}

// ---------------- launch ----------------

extern "C" void kernel_launch(void* const* d_in, const int* in_sizes, int n_in,
                              void* d_out, int out_size, void* d_ws, size_t ws_size,
                              hipStream_t stream) {
    const float* X     = (const float*)d_in[0];
    const int*   esrc  = (const int*)d_in[1];
    const int*   edst  = (const int*)d_in[2];
    const float* ew    = (const float*)d_in[3];
    const float* Wself = (const float*)d_in[4];
    const float* Wrel  = (const float*)d_in[5];
    const float* bias  = (const float*)d_in[6];
    float* out = (float*)d_out;

    // ws layout (16B-aligned segments), ~125 MB total
    ushort* Zb   = (ushort*)d_ws;               // NKEY*FF bf16 = 102.4 MB
    ushort* Xb   = Zb + (size_t)NKEY * FF;      // NN*FF bf16   = 12.8 MB
    ushort* Wf   = Xb + (size_t)NN * FF;        // 9*FF*UU bf16 = 0.29 MB
    int*    head = (int*)(Wf + 9 * FF * UU);    // NKEY         = 1.6 MB
    int4*   rec  = (int4*)(head + NKEY);        // NET int4     = 7.7 MB

    hipLaunchKernelGGL(prep_kernel,  dim3(NN * FF / 4 / 256), dim3(256), 0, stream,
                       X, Wself, Wrel, Xb, Wf, head);
    hipLaunchKernelGGL(build_kernel, dim3((NET + 255) / 256), dim3(256), 0, stream,
                       esrc, edst, ew, head, rec);
    hipLaunchKernelGGL(agg_kernel,   dim3(NKEY / 16), dim3(256), 0, stream,
                       Xb, head, rec, Zb);
    hipLaunchKernelGGL(gemm_kernel,  dim3((NN / 16 + 3) / 4), dim3(256), 0, stream,
                       Xb, Zb, Wf, bias, out);
}